// Round 1
// baseline (172.146 us; speedup 1.0000x reference)
//
#include <hip/hip_runtime.h>

#define B_    16
#define N_    4096
#define S_    1024
#define K_    32
#define DIN_  64
#define DINC_ 67
#define DOUT_ 64

// ---------------------------------------------------------------------------
// Kernel 1: per-row projection.
//   proj[row,c] = bias[c] + dot(xc_row, w1[c,:]) + (use_x ? dot(x_row, w2[c,:]) : 0)
//   xp[row,c]   = dot(x_row, w2[c,:])
// wave = 64 lanes = 64 output channels; per-lane weights live in VGPRs.
// Row activations are wave-uniform loads (readfirstlane'd row id).
// ---------------------------------------------------------------------------
__global__ __launch_bounds__(256) void proj_kernel(
    const float* __restrict__ x, const float* __restrict__ xcm,
    const float* __restrict__ w1, const float* __restrict__ w2,
    const float* __restrict__ bias, const int* __restrict__ use_x_p,
    float* __restrict__ proj, float* __restrict__ xp)
{
    const int lane   = threadIdx.x & 63;
    const int wave   = blockIdx.x * (blockDim.x >> 6) + (threadIdx.x >> 6);
    const int nwaves = gridDim.x * (blockDim.x >> 6);
    const int ux     = use_x_p[0];

    float W1[DINC_];
#pragma unroll
    for (int j = 0; j < DINC_; ++j) W1[j] = w1[lane * DINC_ + j];
    float W2[DIN_];
#pragma unroll
    for (int j = 0; j < DIN_; ++j) W2[j] = w2[lane * DIN_ + j];
    const float bv = bias[lane];

    const int rows = B_ * N_;
    for (int row = wave; row < rows; row += nwaves) {
        // row is wave-uniform in value; make it SGPR so activation loads scalarize
        const int row_u = __builtin_amdgcn_readfirstlane(row);
        const float* xc_row = xcm + (size_t)row_u * DINC_;
        const float* x_row  = x   + (size_t)row_u * DIN_;

        float a1 = bv;
#pragma unroll
        for (int j = 0; j < DINC_; ++j) a1 += xc_row[j] * W1[j];
        float a2 = 0.f;
#pragma unroll
        for (int j = 0; j < DIN_; ++j) a2 += x_row[j] * W2[j];

        const size_t o = (size_t)row_u * DOUT_ + lane;
        xp[o]   = a2;
        proj[o] = ux ? (a1 + a2) : a1;
    }
}

// ---------------------------------------------------------------------------
// Kernel 2: gather + masked max + center subtraction.
// One wave per (b,s) pair; lane = channel. 32 independent coalesced 256B
// row gathers (clamped index + -inf mask for the rare idx==-1).
// ---------------------------------------------------------------------------
__global__ __launch_bounds__(256) void gather_max_kernel(
    const int* __restrict__ indexes, const float* __restrict__ proj,
    const float* __restrict__ xp, const int* __restrict__ use_x_p,
    float* __restrict__ out)
{
    const int lane = threadIdx.x & 63;
    const int pair = blockIdx.x * (blockDim.x >> 6) + (threadIdx.x >> 6); // b*S + s
    const int b    = pair >> 10;   // S_ = 1024
    const int ux   = use_x_p[0];

    const int* idxp = indexes + (size_t)pair * K_;
    const int myidx = idxp[lane & 31];           // lane k<32 holds idx[k]

    const float* projb = proj + (size_t)b * N_ * DOUT_;

    const float NEG = -__builtin_inff();
    float m = NEG;
#pragma unroll
    for (int k = 0; k < K_; ++k) {
        const int ik  = __shfl(myidx, k, 64);    // wave-uniform broadcast
        const int iku = ik < 0 ? 0 : ik;
        const float v = projb[(size_t)iku * DOUT_ + lane];
        m = fmaxf(m, ik < 0 ? NEG : v);
    }
    if (ux) {
        const int i0 = __shfl(myidx, 0, 64);     // always valid per reference
        m -= xp[((size_t)b * N_ + i0) * DOUT_ + lane];
    }
    out[(size_t)pair * DOUT_ + lane] = m;
}

// ---------------------------------------------------------------------------
// Fallback (ws too small): fully fused, recomputes projections per gather.
// One wave per (b,s) pair; ~8.8 GFLOP total — slow but correct.
// ---------------------------------------------------------------------------
__global__ __launch_bounds__(256) void fused_fallback_kernel(
    const float* __restrict__ x, const float* __restrict__ xcm,
    const int* __restrict__ indexes,
    const float* __restrict__ w1, const float* __restrict__ w2,
    const float* __restrict__ bias, const int* __restrict__ use_x_p,
    float* __restrict__ out)
{
    const int lane = threadIdx.x & 63;
    const int pair = blockIdx.x * (blockDim.x >> 6) + (threadIdx.x >> 6);
    const int b    = pair >> 10;
    const int ux   = use_x_p[0];

    float W1[DINC_];
#pragma unroll
    for (int j = 0; j < DINC_; ++j) W1[j] = w1[lane * DINC_ + j];
    float W2[DIN_];
#pragma unroll
    for (int j = 0; j < DIN_; ++j) W2[j] = w2[lane * DIN_ + j];
    const float bv = bias[lane];

    const int* idxp = indexes + (size_t)pair * K_;
    const int myidx = idxp[lane & 31];

    const float NEG = -__builtin_inff();
    float m = NEG;
    for (int k = 0; k < K_; ++k) {
        const int ik = __shfl(myidx, k, 64);
        if (ik < 0) continue;                    // wave-uniform branch
        const float* xc_row = xcm + ((size_t)b * N_ + ik) * DINC_;
        float a1 = bv;
#pragma unroll
        for (int j = 0; j < DINC_; ++j) a1 += xc_row[j] * W1[j];
        if (ux) {
            const float* x_row = x + ((size_t)b * N_ + ik) * DIN_;
            float a2 = 0.f;
#pragma unroll
            for (int j = 0; j < DIN_; ++j) a2 += x_row[j] * W2[j];
            a1 += a2;
        }
        m = fmaxf(m, a1);
    }
    if (ux) {
        const int i0 = __shfl(myidx, 0, 64);
        const float* x_row = x + ((size_t)b * N_ + i0) * DIN_;
        float a2 = 0.f;
#pragma unroll
        for (int j = 0; j < DIN_; ++j) a2 += x_row[j] * W2[j];
        m -= a2;
    }
    out[(size_t)pair * DOUT_ + lane] = m;
}

extern "C" void kernel_launch(void* const* d_in, const int* in_sizes, int n_in,
                              void* d_out, int out_size, void* d_ws, size_t ws_size,
                              hipStream_t stream)
{
    const float* x    = (const float*)d_in[0];
    const float* xcm  = (const float*)d_in[1];
    const int*   idx  = (const int*)d_in[2];
    const float* w1   = (const float*)d_in[3];
    const float* w2   = (const float*)d_in[4];
    const float* bias = (const float*)d_in[5];
    const int*   ux   = (const int*)d_in[6];
    float* out = (float*)d_out;

    const size_t rows    = (size_t)B_ * N_;
    const size_t ws_need = 2 * rows * DOUT_ * sizeof(float);   // proj + xp, 32 MiB
    const int npairs = B_ * S_;                                // 16384

    if (ws_size >= ws_need) {
        float* proj = (float*)d_ws;
        float* xp   = proj + rows * DOUT_;
        // 1024 blocks * 4 waves = 4096 waves; 16 rows each (grid-stride)
        proj_kernel<<<1024, 256, 0, stream>>>(x, xcm, w1, w2, bias, ux, proj, xp);
        gather_max_kernel<<<npairs / 4, 256, 0, stream>>>(idx, proj, xp, ux, out);
    } else {
        fused_fallback_kernel<<<npairs / 4, 256, 0, stream>>>(x, xcm, idx, w1, w2,
                                                              bias, ux, out);
    }
}

// Round 2
// 142.955 us; speedup vs baseline: 1.2042x; 1.2042x over previous
//
#include <hip/hip_runtime.h>

#define B_    16
#define N_    4096
#define S_    1024
#define K_    32
#define DIN_  64
#define DINC_ 67
#define DOUT_ 64

// ---------------------------------------------------------------------------
// Kernel 1: per-row projection.
//   proj[row,c] = bias[c] + dot(xc_row, w1[c,:]) + use_x * dot(x_row, w2[c,:])
//   xp[row,c]   = dot(x_row, w2[c,:])
// wave = 64 lanes = 64 output channels. The 131 per-lane weights MUST stay in
// VGPRs: __launch_bounds__(256,1) unlocks the register budget (~160 VGPR ->
// 3 waves/SIMD, which is enough for a compute-bound loop).
// Activations are wave-uniform loads (readfirstlane'd row id -> scalarizable).
// ---------------------------------------------------------------------------
__global__ __launch_bounds__(256, 1) void proj_kernel(
    const float* __restrict__ x, const float* __restrict__ xcm,
    const float* __restrict__ w1, const float* __restrict__ w2,
    const float* __restrict__ bias, const int* __restrict__ use_x_p,
    float* __restrict__ proj, float* __restrict__ xp)
{
    const int lane   = threadIdx.x & 63;
    const int wave   = (blockIdx.x * blockDim.x + threadIdx.x) >> 6;
    const int nwaves = (gridDim.x * blockDim.x) >> 6;
    const int ux     = use_x_p[0];

    // Per-lane weights: lane = output channel. 131 VGPRs, loaded once.
    float W1[DINC_];
#pragma unroll
    for (int j = 0; j < DINC_; ++j) W1[j] = w1[lane * DINC_ + j];
    float W2[DIN_];
#pragma unroll
    for (int j = 0; j < DIN_; ++j) W2[j] = w2[lane * DIN_ + j];
    const float bv = bias[lane];

    const int rows = B_ * N_;
    for (int row = wave; row < rows; row += nwaves) {
        const int row_u = __builtin_amdgcn_readfirstlane(row);
        const float*  xc_row = xcm + (size_t)row_u * DINC_;
        const float4* x_row4 = (const float4*)(x + (size_t)row_u * DIN_);

        float a1 = bv;
#pragma unroll
        for (int j = 0; j < DINC_; ++j) a1 += xc_row[j] * W1[j];

        float a2 = 0.f;
#pragma unroll
        for (int j4 = 0; j4 < DIN_ / 4; ++j4) {
            const float4 v = x_row4[j4];
            a2 += v.x * W2[4 * j4 + 0];
            a2 += v.y * W2[4 * j4 + 1];
            a2 += v.z * W2[4 * j4 + 2];
            a2 += v.w * W2[4 * j4 + 3];
        }

        const size_t o = (size_t)row_u * DOUT_ + lane;
        xp[o]   = a2;
        proj[o] = ux ? (a1 + a2) : a1;
    }
}

// ---------------------------------------------------------------------------
// Kernel 2: gather + masked max + center subtraction, float4-wide.
// One wave per (b,s). lane = (q, li): q = lane>>4 picks a k-subset of 8,
// li = lane&15 picks 4 channels. Each global_load_dwordx4 gathers 4 distinct
// rows x 256B = 1KB fully used. Cross-quad max via 2 shfl_xor rounds.
// ---------------------------------------------------------------------------
__global__ __launch_bounds__(256) void gather_max_kernel(
    const int* __restrict__ indexes, const float* __restrict__ proj,
    const float* __restrict__ xp, const int* __restrict__ use_x_p,
    float* __restrict__ out)
{
    const int lane = threadIdx.x & 63;
    const int pair = (blockIdx.x * blockDim.x + threadIdx.x) >> 6; // b*S + s
    const int b    = pair >> 10;   // S_ = 1024
    const int q    = lane >> 4;
    const int li   = lane & 15;
    const int ux   = use_x_p[0];

    const int* idxp  = indexes + (size_t)pair * K_;
    const int  myidx = idxp[lane & 31];          // lane k<32 holds idx[k]

    const float* projb = proj + (size_t)b * N_ * DOUT_;
    const float  NEG   = -__builtin_inff();

    float mx = NEG, my = NEG, mz = NEG, mw = NEG;
#pragma unroll
    for (int t = 0; t < 8; ++t) {
        const int k   = q * 8 + t;
        const int ik  = __shfl(myidx, k, 64);     // per-lane src (q) -> bpermute
        const int iku = ik < 0 ? 0 : ik;
        const float4 v = *(const float4*)(projb + (size_t)iku * DOUT_ + li * 4);
        mx = fmaxf(mx, ik < 0 ? NEG : v.x);
        my = fmaxf(my, ik < 0 ? NEG : v.y);
        mz = fmaxf(mz, ik < 0 ? NEG : v.z);
        mw = fmaxf(mw, ik < 0 ? NEG : v.w);
    }
    // reduce across the 4 quads (lanes li, li+16, li+32, li+48)
#pragma unroll
    for (int off = 16; off < 64; off <<= 1) {
        mx = fmaxf(mx, __shfl_xor(mx, off, 64));
        my = fmaxf(my, __shfl_xor(my, off, 64));
        mz = fmaxf(mz, __shfl_xor(mz, off, 64));
        mw = fmaxf(mw, __shfl_xor(mw, off, 64));
    }

    const int i0 = __shfl(myidx, 0, 64);          // center index, always valid
    if (lane < 16) {
        float4 r = make_float4(mx, my, mz, mw);
        if (ux) {
            const float4 c = *(const float4*)(xp + ((size_t)b * N_ + i0) * DOUT_ + li * 4);
            r.x -= c.x; r.y -= c.y; r.z -= c.z; r.w -= c.w;
        }
        *(float4*)(out + (size_t)pair * DOUT_ + li * 4) = r;
    }
}

// ---------------------------------------------------------------------------
// Fallback (ws too small): fully fused, recomputes projections per gather.
// ---------------------------------------------------------------------------
__global__ __launch_bounds__(256, 1) void fused_fallback_kernel(
    const float* __restrict__ x, const float* __restrict__ xcm,
    const int* __restrict__ indexes,
    const float* __restrict__ w1, const float* __restrict__ w2,
    const float* __restrict__ bias, const int* __restrict__ use_x_p,
    float* __restrict__ out)
{
    const int lane = threadIdx.x & 63;
    const int pair = (blockIdx.x * blockDim.x + threadIdx.x) >> 6;
    const int b    = pair >> 10;
    const int ux   = use_x_p[0];

    float W1[DINC_];
#pragma unroll
    for (int j = 0; j < DINC_; ++j) W1[j] = w1[lane * DINC_ + j];
    float W2[DIN_];
#pragma unroll
    for (int j = 0; j < DIN_; ++j) W2[j] = w2[lane * DIN_ + j];
    const float bv = bias[lane];

    const int* idxp  = indexes + (size_t)pair * K_;
    const int  myidx = idxp[lane & 31];

    const float NEG = -__builtin_inff();
    float m = NEG;
    for (int k = 0; k < K_; ++k) {
        const int ik = __shfl(myidx, k, 64);
        if (ik < 0) continue;
        const float* xc_row = xcm + ((size_t)b * N_ + ik) * DINC_;
        float a1 = bv;
#pragma unroll
        for (int j = 0; j < DINC_; ++j) a1 += xc_row[j] * W1[j];
        if (ux) {
            const float* x_row = x + ((size_t)b * N_ + ik) * DIN_;
            float a2 = 0.f;
#pragma unroll
            for (int j = 0; j < DIN_; ++j) a2 += x_row[j] * W2[j];
            a1 += a2;
        }
        m = fmaxf(m, a1);
    }
    if (ux) {
        const int i0 = __shfl(myidx, 0, 64);
        const float* x_row = x + ((size_t)b * N_ + i0) * DIN_;
        float a2 = 0.f;
#pragma unroll
        for (int j = 0; j < DIN_; ++j) a2 += x_row[j] * W2[j];
        m -= a2;
    }
    out[(size_t)pair * DOUT_ + lane] = m;
}

extern "C" void kernel_launch(void* const* d_in, const int* in_sizes, int n_in,
                              void* d_out, int out_size, void* d_ws, size_t ws_size,
                              hipStream_t stream)
{
    const float* x    = (const float*)d_in[0];
    const float* xcm  = (const float*)d_in[1];
    const int*   idx  = (const int*)d_in[2];
    const float* w1   = (const float*)d_in[3];
    const float* w2   = (const float*)d_in[4];
    const float* bias = (const float*)d_in[5];
    const int*   ux   = (const int*)d_in[6];
    float* out = (float*)d_out;

    const size_t rows    = (size_t)B_ * N_;
    const size_t ws_need = 2 * rows * DOUT_ * sizeof(float);   // proj + xp, 32 MiB
    const int npairs = B_ * S_;                                // 16384

    if (ws_size >= ws_need) {
        float* proj = (float*)d_ws;
        float* xp   = proj + rows * DOUT_;
        // 3072 waves: ~21 rows each (weight load amortized), ~3 waves/SIMD resident
        proj_kernel<<<768, 256, 0, stream>>>(x, xcm, w1, w2, bias, ux, proj, xp);
        gather_max_kernel<<<npairs / 4, 256, 0, stream>>>(idx, proj, xp, ux, out);
    } else {
        fused_fallback_kernel<<<npairs / 4, 256, 0, stream>>>(x, xcm, idx, w1, w2,
                                                              bias, ux, out);
    }
}